// Round 6
// baseline (1709.649 us; speedup 1.0000x reference)
//
#include <hip/hip_runtime.h>
#include <hip/hip_bf16.h>

#define NN 100000
#define EE 500000
#define NP 100096  // NN padded to 782*128

typedef __attribute__((ext_vector_type(8))) short bf16x8;
typedef __attribute__((ext_vector_type(4))) float f32x4;

__device__ inline unsigned short f2bf(float f) {
  union { float f; unsigned int u; } v; v.f = f;
  unsigned int r = v.u + 0x7FFFu + ((v.u >> 16) & 1u);
  return (unsigned short)(r >> 16);
}
__device__ inline float bf2f(unsigned short b) {
  union { unsigned int u; float f; } v; v.u = ((unsigned int)b) << 16;
  return v.f;
}
__device__ inline void split_bf(float v, unsigned short& hi, unsigned short& lo) {
  hi = f2bf(v);
  lo = f2bf(v - bf2f(hi));
}

// ---------------- prep: W1 (L,128,256) -> w1 hi/lo [l][n][k] (k contig); W2 (L,256,128) -> w2 hi/lo [l][i][j] (j contig)
__global__ __launch_bounds__(256) void prep_kernel(const float* __restrict__ W1,
                                                   const float* __restrict__ W2,
                                                   unsigned short* __restrict__ w1h,
                                                   unsigned short* __restrict__ w1l,
                                                   unsigned short* __restrict__ w2h,
                                                   unsigned short* __restrict__ w2l) {
  int gid = blockIdx.x * 256 + threadIdx.x;
  if (gid < 5 * 128 * 256) {
    int l = gid / 32768; int rem = gid % 32768;
    int k = rem / 256;   int n = rem % 256;
    unsigned short hi, lo;
    split_bf(W1[gid], hi, lo);
    w1h[l * 32768 + n * 128 + k] = hi;
    w1l[l * 32768 + n * 128 + k] = lo;
  } else if (gid < 2 * 5 * 128 * 256) {
    int g = gid - 163840;
    int l = g / 32768; int rem = g % 32768;
    int j = rem / 128; int i = rem % 128;
    unsigned short hi, lo;
    split_bf(W2[g], hi, lo);
    w2h[l * 32768 + i * 256 + j] = hi;
    w2l[l * 32768 + i * 256 + j] = lo;
  }
}

// ---------------- CSR build ----------------
__global__ __launch_bounds__(256) void zero_deg_kernel(int* __restrict__ deg) {
  int i = blockIdx.x * 256 + threadIdx.x;
  if (i < NN) deg[i] = 0;
}

__global__ __launch_bounds__(256) void hist_kernel(const int* __restrict__ ei, int* __restrict__ deg) {
  int e = blockIdx.x * 256 + threadIdx.x;
  if (e < EE) atomicAdd(&deg[ei[EE + e]], 1);
}

__global__ __launch_bounds__(256) void scan1_kernel(const int* __restrict__ deg,
                                                    int* __restrict__ offs,
                                                    int* __restrict__ bsum) {
  __shared__ int sh[256];
  int b = blockIdx.x, t = threadIdx.x;
  int base = b * 1024 + t * 4;
  int v[4];
  int s = 0;
#pragma unroll
  for (int i = 0; i < 4; ++i) { v[i] = (base + i < NN) ? deg[base + i] : 0; s += v[i]; }
  sh[t] = s;
  __syncthreads();
  for (int off = 1; off < 256; off <<= 1) {
    int x = (t >= off) ? sh[t - off] : 0;
    __syncthreads();
    sh[t] += x;
    __syncthreads();
  }
  int excl = sh[t] - s;
  if (t == 255) bsum[b] = sh[255];
  int run = excl;
#pragma unroll
  for (int i = 0; i < 4; ++i) {
    if (base + i < NN) offs[base + i] = run;
    run += v[i];
  }
}

__global__ void scan2_kernel(int* __restrict__ bsum, int nb) {
  if (threadIdx.x == 0 && blockIdx.x == 0) {
    int run = 0;
    for (int i = 0; i < nb; ++i) { int v = bsum[i]; bsum[i] = run; run += v; }
  }
}

__global__ __launch_bounds__(256) void scan3_kernel(int* __restrict__ offs,
                                                    const int* __restrict__ bsum,
                                                    int* __restrict__ cursor) {
  int i = blockIdx.x * 256 + threadIdx.x;
  if (i < NN) {
    int v = offs[i] + bsum[i >> 10];
    offs[i] = v;
    cursor[i] = v;
  } else if (i == NN) {
    offs[NN] = EE;
  }
}

// pk = src(17b) | a0<<17 | a1<<20 | a2<<23 ; wsrt = edge weight
__global__ __launch_bounds__(256) void scatter_kernel(const int* __restrict__ ei,
                                                      const int* __restrict__ ea,
                                                      const float* __restrict__ ew,
                                                      int* __restrict__ cursor,
                                                      int* __restrict__ pk,
                                                      float* __restrict__ wsrt) {
  int e = blockIdx.x * 256 + threadIdx.x;
  if (e >= EE) return;
  int dst = ei[EE + e];
  int pos = atomicAdd(&cursor[dst], 1);
  int src = ei[e];
  int a0 = ea[e * 3 + 0], a1 = ea[e * 3 + 1], a2 = ea[e * 3 + 2];
  pk[pos] = src | (a0 << 17) | (a1 << 20) | (a2 << 23);
  wsrt[pos] = ew[e];
}

// ---------------- atom embedding: h[n,d] = sum_f atom_emb[f, x[n,f], d] ----------------
__global__ __launch_bounds__(256) void atom_kernel(const int* __restrict__ x,
                                                   const float* __restrict__ aemb,
                                                   float* __restrict__ h) {
  int gid = blockIdx.x * 256 + threadIdx.x;
  int n = gid >> 5, qq = gid & 31;
  if (n >= NN) return;
  float4 s = {0.f, 0.f, 0.f, 0.f};
#pragma unroll
  for (int f = 0; f < 9; ++f) {
    int xi = x[n * 9 + f];
    float4 v = *(const float4*)(aemb + (f * 120 + xi) * 128 + qq * 4);
    s.x += v.x; s.y += v.y; s.z += v.z; s.w += v.w;
  }
  *(float4*)(h + (long)n * 128 + qq * 4) = s;
}

// ---------------- edge aggregate (CSR, no atomics):
// z[n] = (1+eps[l])*h[n] + sum relu(h[src]+bond_e)*w_e ; split hi/lo bf16; zero-fill pad rows
__global__ __launch_bounds__(256) void edge_agg_kernel(const int* __restrict__ offs,
                                                       const int* __restrict__ pk,
                                                       const float* __restrict__ wsrt,
                                                       const float* __restrict__ bemb, // + l*3072
                                                       const float* __restrict__ eps, int l,
                                                       const float* __restrict__ h,
                                                       unsigned short* __restrict__ zh,
                                                       unsigned short* __restrict__ zl) {
  int gid = blockIdx.x * 256 + threadIdx.x; // grid covers NP nodes exactly
  int n = gid >> 5, qq = gid & 31;
  if (n >= NN) { // pad rows: zero so GEMM fragment loads are branch-free
    ushort4 z4 = {0, 0, 0, 0};
    *(ushort4*)(zh + (long)n * 128 + qq * 4) = z4;
    *(ushort4*)(zl + (long)n * 128 + qq * 4) = z4;
    return;
  }
  int s0 = offs[n], s1 = offs[n + 1];
  float e1 = 1.f + eps[l];
  float4 hn = *(const float4*)(h + (long)n * 128 + qq * 4);
  float4 acc = {hn.x * e1, hn.y * e1, hn.z * e1, hn.w * e1};
  for (int e = s0; e < s1; ++e) {
    int p = pk[e];
    float w = wsrt[e];
    int src = p & 131071;
    float4 b0 = *(const float4*)(bemb + (((p >> 17) & 7)) * 128 + qq * 4);
    float4 b1 = *(const float4*)(bemb + (8 + ((p >> 20) & 7)) * 128 + qq * 4);
    float4 b2 = *(const float4*)(bemb + (16 + ((p >> 23) & 7)) * 128 + qq * 4);
    float4 hv = *(const float4*)(h + (long)src * 128 + qq * 4);
    acc.x += fmaxf(hv.x + b0.x + b1.x + b2.x, 0.f) * w;
    acc.y += fmaxf(hv.y + b0.y + b1.y + b2.y, 0.f) * w;
    acc.z += fmaxf(hv.z + b0.z + b1.z + b2.z, 0.f) * w;
    acc.w += fmaxf(hv.w + b0.w + b1.w + b2.w, 0.f) * w;
  }
  ushort4 h4, l4;
  split_bf(acc.x, h4.x, l4.x); split_bf(acc.y, h4.y, l4.y);
  split_bf(acc.z, h4.z, l4.z); split_bf(acc.w, h4.w, l4.w);
  *(ushort4*)(zh + (long)n * 128 + qq * 4) = h4;
  *(ushort4*)(zl + (long)n * 128 + qq * 4) = l4;
}

// ---------------- zero stats (1536 floats)
__global__ void zero_kernel(float* __restrict__ p) {
  for (int i = threadIdx.x; i < 1536; i += 256) p[i] = 0.f;
}

// ---------------- GEMM1 (register-only, sw-pipelined): t1 = z @ W1, split-bf16
// Branch-free fragment loads (rows padded to NP); distance-1 prefetch of next K-chunk.
__global__ __launch_bounds__(256) void gemm1_kernel(const unsigned short* __restrict__ zh,
                                                    const unsigned short* __restrict__ zl,
                                                    const unsigned short* __restrict__ w1h,
                                                    const unsigned short* __restrict__ w1l,
                                                    unsigned short* __restrict__ t1h,
                                                    float* __restrict__ sum1,
                                                    float* __restrict__ sq1) {
  const int tid = threadIdx.x;
  const int lane = tid & 63, w = tid >> 6;
  const int wr = w >> 1, wc = w & 1;
  const int m = lane & 15, q = lane >> 4;
  const int rbase = blockIdx.x * 128;
  const int cb = blockIdx.y;
  f32x4 acc[4][4];
  const f32x4 zf = {0.f, 0.f, 0.f, 0.f};
#pragma unroll
  for (int a = 0; a < 4; ++a)
#pragma unroll
    for (int b = 0; b < 4; ++b) acc[a][b] = zf;

  long aoff[4], boff[4];
#pragma unroll
  for (int rt = 0; rt < 4; ++rt)
    aoff[rt] = (long)(rbase + wr * 64 + rt * 16 + m) * 128 + q * 8;
#pragma unroll
  for (int ct = 0; ct < 4; ++ct)
    boff[ct] = (long)(cb * 128 + wc * 64 + ct * 16 + m) * 128 + q * 8;

  bf16x8 ah[2][4], al[2][4], bh[2][4], bl[2][4];
#pragma unroll
  for (int rt = 0; rt < 4; ++rt) {
    ah[0][rt] = *(const bf16x8*)(zh + aoff[rt]);
    al[0][rt] = *(const bf16x8*)(zl + aoff[rt]);
  }
#pragma unroll
  for (int ct = 0; ct < 4; ++ct) {
    bh[0][ct] = *(const bf16x8*)(w1h + boff[ct]);
    bl[0][ct] = *(const bf16x8*)(w1l + boff[ct]);
  }

#pragma unroll
  for (int c = 0; c < 4; ++c) { // K = 128, chunks of 32
    const int cur = c & 1, nxt = cur ^ 1;
    if (c < 3) { // prefetch next chunk while current MFMAs run
#pragma unroll
      for (int rt = 0; rt < 4; ++rt) {
        ah[nxt][rt] = *(const bf16x8*)(zh + aoff[rt] + (c + 1) * 32);
        al[nxt][rt] = *(const bf16x8*)(zl + aoff[rt] + (c + 1) * 32);
      }
#pragma unroll
      for (int ct = 0; ct < 4; ++ct) {
        bh[nxt][ct] = *(const bf16x8*)(w1h + boff[ct] + (c + 1) * 32);
        bl[nxt][ct] = *(const bf16x8*)(w1l + boff[ct] + (c + 1) * 32);
      }
    }
#pragma unroll
    for (int rt = 0; rt < 4; ++rt)
#pragma unroll
      for (int ct = 0; ct < 4; ++ct) {
        acc[rt][ct] = __builtin_amdgcn_mfma_f32_16x16x32_bf16(ah[cur][rt], bh[cur][ct], acc[rt][ct], 0, 0, 0);
        acc[rt][ct] = __builtin_amdgcn_mfma_f32_16x16x32_bf16(al[cur][rt], bh[cur][ct], acc[rt][ct], 0, 0, 0);
        acc[rt][ct] = __builtin_amdgcn_mfma_f32_16x16x32_bf16(ah[cur][rt], bl[cur][ct], acc[rt][ct], 0, 0, 0);
      }
  }
  // epilogue: bf16 store (t1h padded -> unmasked) + column stats
#pragma unroll
  for (int ct = 0; ct < 4; ++ct) {
    int gc = cb * 128 + wc * 64 + ct * 16 + m;
    float s = 0.f, s2 = 0.f;
#pragma unroll
    for (int rt = 0; rt < 4; ++rt) {
      int grow = rbase + wr * 64 + rt * 16 + q * 4;
#pragma unroll
      for (int i = 0; i < 4; ++i) {
        float v = acc[rt][ct][i];
        s += v; s2 += v * v;
        t1h[(long)(grow + i) * 256 + gc] = f2bf(v);
      }
    }
    s  += __shfl_xor(s, 16);  s  += __shfl_xor(s, 32);
    s2 += __shfl_xor(s2, 16); s2 += __shfl_xor(s2, 32);
    if (q == 0) { unsafeAtomicAdd(&sum1[gc], s); unsafeAtomicAdd(&sq1[gc], s2); }
  }
}

// ---------------- stats: scale = g*rsqrt(var+eps), shift = bt - mu*scale
__global__ void stats_kernel(const float* __restrict__ sum, const float* __restrict__ sq,
                             const float* __restrict__ g, const float* __restrict__ bt,
                             float* __restrict__ scale, float* __restrict__ shift, int C) {
  int j = blockIdx.x * blockDim.x + threadIdx.x;
  if (j >= C) return;
  float mu = sum[j] * (1.f / NN);
  float var = sq[j] * (1.f / NN) - mu * mu;
  var = fmaxf(var, 0.f);
  float is = rsqrtf(var + 1e-5f);
  float sc = g[j] * is;
  scale[j] = sc;
  shift[j] = bt[j] - mu * sc;
}

// ---------------- bnapply: a1 = relu(BN1(t1)) split hi/lo.
// a1l written IN-PLACE over t1h (elementwise); pad rows forced to zero.
__global__ __launch_bounds__(256) void bnapply_kernel(unsigned short* t1h, // in: t1 hi; out: a1 lo
                                                      unsigned short* __restrict__ a1h,
                                                      const float* __restrict__ scale1,
                                                      const float* __restrict__ shift1) {
  long idx = (long)(blockIdx.x * 256 + threadIdx.x) * 8; // NP*256 elems exactly
  int row = (int)(idx >> 8);
  if (row >= NN) {
    ushort4 z4 = {0, 0, 0, 0};
    *(ushort4*)(a1h + idx) = z4; *(ushort4*)(a1h + idx + 4) = z4;
    *(ushort4*)(t1h + idx) = z4; *(ushort4*)(t1h + idx + 4) = z4;
    return;
  }
  int j0 = (int)(idx & 255);
  float4 sc0 = *(const float4*)(scale1 + j0);
  float4 sc1 = *(const float4*)(scale1 + j0 + 4);
  float4 sh0 = *(const float4*)(shift1 + j0);
  float4 sh1 = *(const float4*)(shift1 + j0 + 4);
  ushort4 u0 = *(const ushort4*)(t1h + idx);
  ushort4 u1 = *(const ushort4*)(t1h + idx + 4);
  float a0 = fmaxf(bf2f(u0.x) * sc0.x + sh0.x, 0.f);
  float a1 = fmaxf(bf2f(u0.y) * sc0.y + sh0.y, 0.f);
  float a2 = fmaxf(bf2f(u0.z) * sc0.z + sh0.z, 0.f);
  float a3 = fmaxf(bf2f(u0.w) * sc0.w + sh0.w, 0.f);
  float a4 = fmaxf(bf2f(u1.x) * sc1.x + sh1.x, 0.f);
  float a5 = fmaxf(bf2f(u1.y) * sc1.y + sh1.y, 0.f);
  float a6 = fmaxf(bf2f(u1.z) * sc1.z + sh1.z, 0.f);
  float a7 = fmaxf(bf2f(u1.w) * sc1.w + sh1.w, 0.f);
  ushort4 h0, l0, h1, l1;
  split_bf(a0, h0.x, l0.x); split_bf(a1, h0.y, l0.y);
  split_bf(a2, h0.z, l0.z); split_bf(a3, h0.w, l0.w);
  split_bf(a4, h1.x, l1.x); split_bf(a5, h1.y, l1.y);
  split_bf(a6, h1.z, l1.z); split_bf(a7, h1.w, l1.w);
  *(ushort4*)(a1h + idx) = h0;
  *(ushort4*)(a1h + idx + 4) = h1;
  *(ushort4*)(t1h + idx) = l0;
  *(ushort4*)(t1h + idx + 4) = l1;
}

// ---------------- GEMM2 (register-only, sw-pipelined): t2 = a1 @ W2; t2 f32 -> h buffer (d_out)
__global__ __launch_bounds__(256) void gemm2_kernel(const unsigned short* __restrict__ a1h,
                                                    const unsigned short* __restrict__ a1l,
                                                    const unsigned short* __restrict__ w2h,
                                                    const unsigned short* __restrict__ w2l,
                                                    float* __restrict__ t2,
                                                    float* __restrict__ sum2,
                                                    float* __restrict__ sq2) {
  const int tid = threadIdx.x;
  const int lane = tid & 63, w = tid >> 6;
  const int wr = w >> 1, wc = w & 1;
  const int m = lane & 15, q = lane >> 4;
  const int rbase = blockIdx.x * 128;
  f32x4 acc[4][4];
  const f32x4 zf = {0.f, 0.f, 0.f, 0.f};
#pragma unroll
  for (int a = 0; a < 4; ++a)
#pragma unroll
    for (int b = 0; b < 4; ++b) acc[a][b] = zf;

  long aoff[4], boff[4];
#pragma unroll
  for (int rt = 0; rt < 4; ++rt)
    aoff[rt] = (long)(rbase + wr * 64 + rt * 16 + m) * 256 + q * 8;
#pragma unroll
  for (int ct = 0; ct < 4; ++ct)
    boff[ct] = (long)(wc * 64 + ct * 16 + m) * 256 + q * 8;

  bf16x8 ah[2][4], al[2][4], bh[2][4], bl[2][4];
#pragma unroll
  for (int rt = 0; rt < 4; ++rt) {
    ah[0][rt] = *(const bf16x8*)(a1h + aoff[rt]);
    al[0][rt] = *(const bf16x8*)(a1l + aoff[rt]);
  }
#pragma unroll
  for (int ct = 0; ct < 4; ++ct) {
    bh[0][ct] = *(const bf16x8*)(w2h + boff[ct]);
    bl[0][ct] = *(const bf16x8*)(w2l + boff[ct]);
  }

#pragma unroll
  for (int c = 0; c < 8; ++c) { // K = 256, chunks of 32
    const int cur = c & 1, nxt = cur ^ 1;
    if (c < 7) {
#pragma unroll
      for (int rt = 0; rt < 4; ++rt) {
        ah[nxt][rt] = *(const bf16x8*)(a1h + aoff[rt] + (c + 1) * 32);
        al[nxt][rt] = *(const bf16x8*)(a1l + aoff[rt] + (c + 1) * 32);
      }
#pragma unroll
      for (int ct = 0; ct < 4; ++ct) {
        bh[nxt][ct] = *(const bf16x8*)(w2h + boff[ct] + (c + 1) * 32);
        bl[nxt][ct] = *(const bf16x8*)(w2l + boff[ct] + (c + 1) * 32);
      }
    }
#pragma unroll
    for (int rt = 0; rt < 4; ++rt)
#pragma unroll
      for (int ct = 0; ct < 4; ++ct) {
        acc[rt][ct] = __builtin_amdgcn_mfma_f32_16x16x32_bf16(ah[cur][rt], bh[cur][ct], acc[rt][ct], 0, 0, 0);
        acc[rt][ct] = __builtin_amdgcn_mfma_f32_16x16x32_bf16(al[cur][rt], bh[cur][ct], acc[rt][ct], 0, 0, 0);
        acc[rt][ct] = __builtin_amdgcn_mfma_f32_16x16x32_bf16(ah[cur][rt], bl[cur][ct], acc[rt][ct], 0, 0, 0);
      }
  }
#pragma unroll
  for (int ct = 0; ct < 4; ++ct) {
    int gc = wc * 64 + ct * 16 + m;
    float s = 0.f, s2 = 0.f;
#pragma unroll
    for (int rt = 0; rt < 4; ++rt) {
      int grow = rbase + wr * 64 + rt * 16 + q * 4;
#pragma unroll
      for (int i = 0; i < 4; ++i) {
        float v = acc[rt][ct][i];
        s += v; s2 += v * v;
        if (grow + i < NN) t2[(long)(grow + i) * 128 + gc] = v; // d_out is exactly N x 128
      }
    }
    s  += __shfl_xor(s, 16);  s  += __shfl_xor(s, 32);
    s2 += __shfl_xor(s2, 16); s2 += __shfl_xor(s2, 32);
    if (q == 0) { unsafeAtomicAdd(&sum2[gc], s); unsafeAtomicAdd(&sq2[gc], s2); }
  }
}

// ---------------- apply (in-place on h buffer): h = BN2(t2), relu unless last
__global__ __launch_bounds__(256) void apply_kernel(float* hv,
                                                    const float* __restrict__ scale2,
                                                    const float* __restrict__ shift2,
                                                    int last) {
  int gid = blockIdx.x * 256 + threadIdx.x;
  int n = gid >> 5, qq = gid & 31;
  if (n >= NN) return;
  float4 u = *(const float4*)(hv + (long)n * 128 + qq * 4);
  float4 sc = *(const float4*)(scale2 + qq * 4);
  float4 sh = *(const float4*)(shift2 + qq * 4);
  float4 y;
  y.x = u.x * sc.x + sh.x;
  y.y = u.y * sc.y + sh.y;
  y.z = u.z * sc.z + sh.z;
  y.w = u.w * sc.w + sh.w;
  if (!last) {
    y.x = fmaxf(y.x, 0.f); y.y = fmaxf(y.y, 0.f);
    y.z = fmaxf(y.z, 0.f); y.w = fmaxf(y.w, 0.f);
  }
  *(float4*)(hv + (long)n * 128 + qq * 4) = y;
}

extern "C" void kernel_launch(void* const* d_in, const int* in_sizes, int n_in,
                              void* d_out, int out_size, void* d_ws, size_t ws_size,
                              hipStream_t stream) {
  (void)in_sizes; (void)n_in; (void)out_size; (void)ws_size;
  const int*   x      = (const int*)d_in[0];
  const int*   ei     = (const int*)d_in[1];
  const int*   ea     = (const int*)d_in[2];
  const float* ew     = (const float*)d_in[3];
  const float* aemb   = (const float*)d_in[4];
  const float* bemb   = (const float*)d_in[5];
  const float* eps    = (const float*)d_in[6];
  const float* W1     = (const float*)d_in[7];
  const float* g1     = (const float*)d_in[9];
  const float* bt1    = (const float*)d_in[10];
  const float* W2     = (const float*)d_in[11];
  const float* g_out  = (const float*)d_in[13];
  const float* bt_out = (const float*)d_in[14];

  float* h = (float*)d_out; // (N,128) f32; also holds t2 f32 between gemm2 and apply

  // ws layout (~109.0 MB; rows padded to NP=100096):
  //   [0, 25,624,576):            zh (NP x 128 bf16)
  //   [25,624,576, 51,249,152):   zl        -- zh+zl region reused as a1h (NP x 256 bf16) after gemm1
  //   [51,249,152, 102,498,304):  t1h (NP x 256 bf16), rewritten in-place as a1l by bnapply
  //   [102,498,304, ...):         weights hi/lo + stats + CSR
  char* ws = (char*)d_ws;
  unsigned short* zh  = (unsigned short*)(ws);
  unsigned short* zl  = (unsigned short*)(ws + 25624576);
  unsigned short* a1h = (unsigned short*)(ws);
  unsigned short* t1h = (unsigned short*)(ws + 51249152); // doubles as a1l
  unsigned short* w1h = (unsigned short*)(ws + 102498304);
  unsigned short* w1l = (unsigned short*)(ws + 102825984);
  unsigned short* w2h = (unsigned short*)(ws + 103153664);
  unsigned short* w2l = (unsigned short*)(ws + 103481344);
  float* stats = (float*)(ws + 103809024);                // 1536 f32 -> ends 103,815,168
  int*   deg    = (int*)(ws + 103815168);                 // 100000 ints
  int*   offs   = (int*)(ws + 104215168);                 // 100001 ints (+pad)
  int*   cursor = (int*)(ws + 104615176);                 // 100000 ints
  int*   bsum   = (int*)(ws + 105015176);                 // 98 ints (pad 400)
  int*   pk     = (int*)(ws + 105015576);                 // 500000 ints
  float* wsrt   = (float*)(ws + 107015576);               // 500000 f32 -> ends 109,015,576

  float* sum1 = stats;          float* sq1 = stats + 256;
  float* scale1 = stats + 512;  float* shift1 = stats + 768;
  float* sum2 = stats + 1024;   float* sq2 = stats + 1152;
  float* scale2 = stats + 1280; float* shift2 = stats + 1408;

  prep_kernel<<<1280, 256, 0, stream>>>(W1, W2, w1h, w1l, w2h, w2l);
  zero_deg_kernel<<<391, 256, 0, stream>>>(deg);
  hist_kernel<<<1954, 256, 0, stream>>>(ei, deg);
  scan1_kernel<<<98, 256, 0, stream>>>(deg, offs, bsum);
  scan2_kernel<<<1, 64, 0, stream>>>(bsum, 98);
  scan3_kernel<<<392, 256, 0, stream>>>(offs, bsum, cursor);
  scatter_kernel<<<1954, 256, 0, stream>>>(ei, ea, ew, cursor, pk, wsrt);
  atom_kernel<<<12500, 256, 0, stream>>>(x, aemb, h);

  for (int l = 0; l < 5; ++l) {
    zero_kernel<<<1, 256, 0, stream>>>(stats);
    edge_agg_kernel<<<12512, 256, 0, stream>>>(offs, pk, wsrt, bemb + l * 3072, eps, l, h, zh, zl);
    gemm1_kernel<<<dim3(782, 2), 256, 0, stream>>>(zh, zl, w1h + l * 32768, w1l + l * 32768, t1h, sum1, sq1);
    stats_kernel<<<1, 256, 0, stream>>>(sum1, sq1, g1 + l * 256, bt1 + l * 256, scale1, shift1, 256);
    bnapply_kernel<<<12512, 256, 0, stream>>>(t1h, a1h, scale1, shift1);
    gemm2_kernel<<<782, 256, 0, stream>>>(a1h, t1h, w2h + l * 32768, w2l + l * 32768, h, sum2, sq2);
    stats_kernel<<<1, 128, 0, stream>>>(sum2, sq2, g_out + l * 128, bt_out + l * 128, scale2, shift2, 128);
    apply_kernel<<<12500, 256, 0, stream>>>(h, scale2, shift2, (l == 4) ? 1 : 0);
  }
}

// Round 7
// 1385.777 us; speedup vs baseline: 1.2337x; 1.2337x over previous
//
#include <hip/hip_runtime.h>
#include <hip/hip_bf16.h>

#define NN 100000
#define EE 500000
#define NP 100096  // NN padded to 1564*64

typedef __attribute__((ext_vector_type(8))) short bf16x8;
typedef __attribute__((ext_vector_type(4))) float f32x4;

__device__ inline unsigned short f2bf(float f) {
  union { float f; unsigned int u; } v; v.f = f;
  unsigned int r = v.u + 0x7FFFu + ((v.u >> 16) & 1u);
  return (unsigned short)(r >> 16);
}
__device__ inline float bf2f(unsigned short b) {
  union { unsigned int u; float f; } v; v.u = ((unsigned int)b) << 16;
  return v.f;
}
__device__ inline void split_bf(float v, unsigned short& hi, unsigned short& lo) {
  hi = f2bf(v);
  lo = f2bf(v - bf2f(hi));
}

// ---------------- prep: W1 (L,128,256) -> w1 hi/lo [l][outcol][k]; W2 (L,256,128) -> w2 hi/lo [l][outcol][k]
__global__ __launch_bounds__(256) void prep_kernel(const float* __restrict__ W1,
                                                   const float* __restrict__ W2,
                                                   unsigned short* __restrict__ w1h,
                                                   unsigned short* __restrict__ w1l,
                                                   unsigned short* __restrict__ w2h,
                                                   unsigned short* __restrict__ w2l) {
  int gid = blockIdx.x * 256 + threadIdx.x;
  if (gid < 5 * 128 * 256) {
    int l = gid / 32768; int rem = gid % 32768;
    int k = rem / 256;   int n = rem % 256;
    unsigned short hi, lo;
    split_bf(W1[gid], hi, lo);
    w1h[l * 32768 + n * 128 + k] = hi;
    w1l[l * 32768 + n * 128 + k] = lo;
  } else if (gid < 2 * 5 * 128 * 256) {
    int g = gid - 163840;
    int l = g / 32768; int rem = g % 32768;
    int j = rem / 128; int i = rem % 128;
    unsigned short hi, lo;
    split_bf(W2[g], hi, lo);
    w2h[l * 32768 + i * 256 + j] = hi;
    w2l[l * 32768 + i * 256 + j] = lo;
  }
}

// ---------------- CSR build ----------------
__global__ __launch_bounds__(256) void zero_deg_kernel(int* __restrict__ deg) {
  int i = blockIdx.x * 256 + threadIdx.x;
  if (i < NN) deg[i] = 0;
}

__global__ __launch_bounds__(256) void hist_kernel(const int* __restrict__ ei, int* __restrict__ deg) {
  int e = blockIdx.x * 256 + threadIdx.x;
  if (e < EE) atomicAdd(&deg[ei[EE + e]], 1);
}

__global__ __launch_bounds__(256) void scan1_kernel(const int* __restrict__ deg,
                                                    int* __restrict__ offs,
                                                    int* __restrict__ bsum) {
  __shared__ int sh[256];
  int b = blockIdx.x, t = threadIdx.x;
  int base = b * 1024 + t * 4;
  int v[4];
  int s = 0;
#pragma unroll
  for (int i = 0; i < 4; ++i) { v[i] = (base + i < NN) ? deg[base + i] : 0; s += v[i]; }
  sh[t] = s;
  __syncthreads();
  for (int off = 1; off < 256; off <<= 1) {
    int x = (t >= off) ? sh[t - off] : 0;
    __syncthreads();
    sh[t] += x;
    __syncthreads();
  }
  int excl = sh[t] - s;
  if (t == 255) bsum[b] = sh[255];
  int run = excl;
#pragma unroll
  for (int i = 0; i < 4; ++i) {
    if (base + i < NN) offs[base + i] = run;
    run += v[i];
  }
}

__global__ void scan2_kernel(int* __restrict__ bsum, int nb) {
  if (threadIdx.x == 0 && blockIdx.x == 0) {
    int run = 0;
    for (int i = 0; i < nb; ++i) { int v = bsum[i]; bsum[i] = run; run += v; }
  }
}

__global__ __launch_bounds__(256) void scan3_kernel(int* __restrict__ offs,
                                                    const int* __restrict__ bsum,
                                                    int* __restrict__ cursor) {
  int i = blockIdx.x * 256 + threadIdx.x;
  if (i < NN) {
    int v = offs[i] + bsum[i >> 10];
    offs[i] = v;
    cursor[i] = v;
  } else if (i == NN) {
    offs[NN] = EE;
  }
}

// pk = src(17b) | a0<<17 | a1<<20 | a2<<23 ; wsrt = edge weight
__global__ __launch_bounds__(256) void scatter_kernel(const int* __restrict__ ei,
                                                      const int* __restrict__ ea,
                                                      const float* __restrict__ ew,
                                                      int* __restrict__ cursor,
                                                      int* __restrict__ pk,
                                                      float* __restrict__ wsrt) {
  int e = blockIdx.x * 256 + threadIdx.x;
  if (e >= EE) return;
  int dst = ei[EE + e];
  int pos = atomicAdd(&cursor[dst], 1);
  int src = ei[e];
  int a0 = ea[e * 3 + 0], a1 = ea[e * 3 + 1], a2 = ea[e * 3 + 2];
  pk[pos] = src | (a0 << 17) | (a1 << 20) | (a2 << 23);
  wsrt[pos] = ew[e];
}

// ---------------- zero the sliced stat accumulators (12288 f32) ----------------
__global__ __launch_bounds__(256) void zero_slices_kernel(float* __restrict__ p) {
  int i = blockIdx.x * 256 + threadIdx.x; // 12 blocks -> 3072 threads * 4
  *(float4*)(p + i * 4) = float4{0.f, 0.f, 0.f, 0.f};
}

// ---------------- atom embedding: h[n,d] = sum_f atom_emb[f, x[n,f], d] ----------------
__global__ __launch_bounds__(256) void atom_kernel(const int* __restrict__ x,
                                                   const float* __restrict__ aemb,
                                                   float* __restrict__ h) {
  int gid = blockIdx.x * 256 + threadIdx.x;
  int n = gid >> 5, qq = gid & 31;
  if (n >= NN) return;
  float4 s = {0.f, 0.f, 0.f, 0.f};
#pragma unroll
  for (int f = 0; f < 9; ++f) {
    int xi = x[n * 9 + f];
    float4 v = *(const float4*)(aemb + (f * 120 + xi) * 128 + qq * 4);
    s.x += v.x; s.y += v.y; s.z += v.z; s.w += v.w;
  }
  *(float4*)(h + (long)n * 128 + qq * 4) = s;
}

// ---------------- edge aggregate (CSR, no atomics):
// z[n] = (1+eps[l])*h[n] + sum relu(h[src]+bond_e)*w_e ; split hi/lo bf16; zero-fill pad rows
__global__ __launch_bounds__(256) void edge_agg_kernel(const int* __restrict__ offs,
                                                       const int* __restrict__ pk,
                                                       const float* __restrict__ wsrt,
                                                       const float* __restrict__ bemb, // + l*3072
                                                       const float* __restrict__ eps, int l,
                                                       const float* __restrict__ h,
                                                       unsigned short* __restrict__ zh,
                                                       unsigned short* __restrict__ zl) {
  int gid = blockIdx.x * 256 + threadIdx.x; // grid covers NP nodes exactly
  int n = gid >> 5, qq = gid & 31;
  if (n >= NN) { // pad rows: zero so GEMM1 fragment loads are branch-free
    ushort4 z4 = {0, 0, 0, 0};
    *(ushort4*)(zh + (long)n * 128 + qq * 4) = z4;
    *(ushort4*)(zl + (long)n * 128 + qq * 4) = z4;
    return;
  }
  int s0 = offs[n], s1 = offs[n + 1];
  float e1 = 1.f + eps[l];
  float4 hn = *(const float4*)(h + (long)n * 128 + qq * 4);
  float4 acc = {hn.x * e1, hn.y * e1, hn.z * e1, hn.w * e1};
  for (int e = s0; e < s1; ++e) {
    int p = pk[e];
    float w = wsrt[e];
    int src = p & 131071;
    float4 b0 = *(const float4*)(bemb + (((p >> 17) & 7)) * 128 + qq * 4);
    float4 b1 = *(const float4*)(bemb + (8 + ((p >> 20) & 7)) * 128 + qq * 4);
    float4 b2 = *(const float4*)(bemb + (16 + ((p >> 23) & 7)) * 128 + qq * 4);
    float4 hv = *(const float4*)(h + (long)src * 128 + qq * 4);
    acc.x += fmaxf(hv.x + b0.x + b1.x + b2.x, 0.f) * w;
    acc.y += fmaxf(hv.y + b0.y + b1.y + b2.y, 0.f) * w;
    acc.z += fmaxf(hv.z + b0.z + b1.z + b2.z, 0.f) * w;
    acc.w += fmaxf(hv.w + b0.w + b1.w + b2.w, 0.f) * w;
  }
  ushort4 h4, l4;
  split_bf(acc.x, h4.x, l4.x); split_bf(acc.y, h4.y, l4.y);
  split_bf(acc.z, h4.z, l4.z); split_bf(acc.w, h4.w, l4.w);
  *(ushort4*)(zh + (long)n * 128 + qq * 4) = h4;
  *(ushort4*)(zl + (long)n * 128 + qq * 4) = l4;
}

// ---------------- GEMM1 (register-only, 64x128 tiles): t1 = z @ W1, split-bf16
// grid (1564, 2); 4 waves of 32x64. Branch-free loads (rows padded). Sliced stats.
__global__ __launch_bounds__(256) void gemm1_kernel(const unsigned short* __restrict__ zh,
                                                    const unsigned short* __restrict__ zl,
                                                    const unsigned short* __restrict__ w1h,
                                                    const unsigned short* __restrict__ w1l,
                                                    unsigned short* __restrict__ t1h,
                                                    float* __restrict__ sum1s,
                                                    float* __restrict__ sq1s) {
  const int tid = threadIdx.x;
  const int lane = tid & 63, w = tid >> 6;
  const int wr = w >> 1, wc = w & 1;
  const int m = lane & 15, q = lane >> 4;
  const int rbase = blockIdx.x * 64;
  const int cb = blockIdx.y;
  const int slice = blockIdx.x & 15;
  f32x4 acc[2][4];
  const f32x4 zf = {0.f, 0.f, 0.f, 0.f};
#pragma unroll
  for (int a = 0; a < 2; ++a)
#pragma unroll
    for (int b = 0; b < 4; ++b) acc[a][b] = zf;

  long aoff[2], boff[4];
#pragma unroll
  for (int rt = 0; rt < 2; ++rt)
    aoff[rt] = (long)(rbase + wr * 32 + rt * 16 + m) * 128 + q * 8;
#pragma unroll
  for (int ct = 0; ct < 4; ++ct)
    boff[ct] = (long)(cb * 128 + wc * 64 + ct * 16 + m) * 128 + q * 8;

#pragma unroll
  for (int c = 0; c < 4; ++c) { // K = 128, chunks of 32
    bf16x8 ah[2], al[2], bh[4], bl[4];
#pragma unroll
    for (int rt = 0; rt < 2; ++rt) {
      ah[rt] = *(const bf16x8*)(zh + aoff[rt] + c * 32);
      al[rt] = *(const bf16x8*)(zl + aoff[rt] + c * 32);
    }
#pragma unroll
    for (int ct = 0; ct < 4; ++ct) {
      bh[ct] = *(const bf16x8*)(w1h + boff[ct] + c * 32);
      bl[ct] = *(const bf16x8*)(w1l + boff[ct] + c * 32);
    }
#pragma unroll
    for (int rt = 0; rt < 2; ++rt)
#pragma unroll
      for (int ct = 0; ct < 4; ++ct) {
        acc[rt][ct] = __builtin_amdgcn_mfma_f32_16x16x32_bf16(ah[rt], bh[ct], acc[rt][ct], 0, 0, 0);
        acc[rt][ct] = __builtin_amdgcn_mfma_f32_16x16x32_bf16(al[rt], bh[ct], acc[rt][ct], 0, 0, 0);
        acc[rt][ct] = __builtin_amdgcn_mfma_f32_16x16x32_bf16(ah[rt], bl[ct], acc[rt][ct], 0, 0, 0);
      }
  }
  // epilogue: bf16 store (t1h padded -> unmasked) + sliced column stats
#pragma unroll
  for (int ct = 0; ct < 4; ++ct) {
    int gc = cb * 128 + wc * 64 + ct * 16 + m;
    float s = 0.f, s2 = 0.f;
#pragma unroll
    for (int rt = 0; rt < 2; ++rt) {
      int grow = rbase + wr * 32 + rt * 16 + q * 4;
#pragma unroll
      for (int i = 0; i < 4; ++i) {
        float v = acc[rt][ct][i];
        s += v; s2 += v * v;
        t1h[(long)(grow + i) * 256 + gc] = f2bf(v);
      }
    }
    s  += __shfl_xor(s, 16);  s  += __shfl_xor(s, 32);
    s2 += __shfl_xor(s2, 16); s2 += __shfl_xor(s2, 32);
    if (q == 0) {
      unsafeAtomicAdd(&sum1s[slice * 256 + gc], s);
      unsafeAtomicAdd(&sq1s[slice * 256 + gc], s2);
    }
  }
}

// ---------------- stats: reduce 16 slices, compute scale/shift, re-zero slices
__global__ void stats_kernel(float* __restrict__ sums, float* __restrict__ sqs,
                             const float* __restrict__ g, const float* __restrict__ bt,
                             float* __restrict__ scale, float* __restrict__ shift, int C) {
  int j = blockIdx.x * blockDim.x + threadIdx.x;
  if (j >= C) return;
  float s = 0.f, s2 = 0.f;
#pragma unroll
  for (int k = 0; k < 16; ++k) {
    s += sums[k * C + j]; s2 += sqs[k * C + j];
    sums[k * C + j] = 0.f; sqs[k * C + j] = 0.f; // ready for next layer
  }
  float mu = s * (1.f / NN);
  float var = s2 * (1.f / NN) - mu * mu;
  var = fmaxf(var, 0.f);
  float is = rsqrtf(var + 1e-5f);
  float sc = g[j] * is;
  scale[j] = sc;
  shift[j] = bt[j] - mu * sc;
}

// ---------------- GEMM2 (register-only, 64x128 tiles, fused BN1+relu+split on A):
// t2 = relu(BN1(t1)) @ W2 ; A read as t1 hi bf16, BN applied in-register. grid 1564.
__global__ __launch_bounds__(256) void gemm2_kernel(const unsigned short* __restrict__ t1h,
                                                    const float* __restrict__ scale1,
                                                    const float* __restrict__ shift1,
                                                    const unsigned short* __restrict__ w2h,
                                                    const unsigned short* __restrict__ w2l,
                                                    float* __restrict__ t2,
                                                    float* __restrict__ sum2s,
                                                    float* __restrict__ sq2s) {
  const int tid = threadIdx.x;
  const int lane = tid & 63, w = tid >> 6;
  const int wr = w >> 1, wc = w & 1;
  const int m = lane & 15, q = lane >> 4;
  const int rbase = blockIdx.x * 64;
  const int slice = blockIdx.x & 15;
  f32x4 acc[2][4];
  const f32x4 zf = {0.f, 0.f, 0.f, 0.f};
#pragma unroll
  for (int a = 0; a < 2; ++a)
#pragma unroll
    for (int b = 0; b < 4; ++b) acc[a][b] = zf;

  long aoff[2]; bool aok[2];
#pragma unroll
  for (int rt = 0; rt < 2; ++rt) {
    int r = rbase + wr * 32 + rt * 16 + m;
    aok[rt] = r < NN; // pad rows must contribute ZERO to acc/stats (BN shift would pollute)
    aoff[rt] = (long)r * 256 + q * 8;
  }
  long boff[4];
#pragma unroll
  for (int ct = 0; ct < 4; ++ct)
    boff[ct] = (long)(wc * 64 + ct * 16 + m) * 256 + q * 8;

#pragma unroll
  for (int c = 0; c < 8; ++c) { // K = 256, chunks of 32
    int k0 = c * 32 + q * 8;
    float4 sc0 = *(const float4*)(scale1 + k0);
    float4 sc1 = *(const float4*)(scale1 + k0 + 4);
    float4 sh0 = *(const float4*)(shift1 + k0);
    float4 sh1 = *(const float4*)(shift1 + k0 + 4);
    bf16x8 ah[2], al[2], bh[4], bl[4];
#pragma unroll
    for (int rt = 0; rt < 2; ++rt) {
      bf16x8 hz = {0, 0, 0, 0, 0, 0, 0, 0};
      bf16x8 lz = {0, 0, 0, 0, 0, 0, 0, 0};
      if (aok[rt]) {
        bf16x8 u = *(const bf16x8*)(t1h + aoff[rt] + c * 32);
        float f0 = fmaxf(bf2f((unsigned short)u[0]) * sc0.x + sh0.x, 0.f);
        float f1 = fmaxf(bf2f((unsigned short)u[1]) * sc0.y + sh0.y, 0.f);
        float f2 = fmaxf(bf2f((unsigned short)u[2]) * sc0.z + sh0.z, 0.f);
        float f3 = fmaxf(bf2f((unsigned short)u[3]) * sc0.w + sh0.w, 0.f);
        float f4 = fmaxf(bf2f((unsigned short)u[4]) * sc1.x + sh1.x, 0.f);
        float f5 = fmaxf(bf2f((unsigned short)u[5]) * sc1.y + sh1.y, 0.f);
        float f6 = fmaxf(bf2f((unsigned short)u[6]) * sc1.z + sh1.z, 0.f);
        float f7 = fmaxf(bf2f((unsigned short)u[7]) * sc1.w + sh1.w, 0.f);
        unsigned short hh, ll;
        split_bf(f0, hh, ll); hz[0] = (short)hh; lz[0] = (short)ll;
        split_bf(f1, hh, ll); hz[1] = (short)hh; lz[1] = (short)ll;
        split_bf(f2, hh, ll); hz[2] = (short)hh; lz[2] = (short)ll;
        split_bf(f3, hh, ll); hz[3] = (short)hh; lz[3] = (short)ll;
        split_bf(f4, hh, ll); hz[4] = (short)hh; lz[4] = (short)ll;
        split_bf(f5, hh, ll); hz[5] = (short)hh; lz[5] = (short)ll;
        split_bf(f6, hh, ll); hz[6] = (short)hh; lz[6] = (short)ll;
        split_bf(f7, hh, ll); hz[7] = (short)hh; lz[7] = (short)ll;
      }
      ah[rt] = hz; al[rt] = lz;
    }
#pragma unroll
    for (int ct = 0; ct < 4; ++ct) {
      bh[ct] = *(const bf16x8*)(w2h + boff[ct] + c * 32);
      bl[ct] = *(const bf16x8*)(w2l + boff[ct] + c * 32);
    }
#pragma unroll
    for (int rt = 0; rt < 2; ++rt)
#pragma unroll
      for (int ct = 0; ct < 4; ++ct) {
        acc[rt][ct] = __builtin_amdgcn_mfma_f32_16x16x32_bf16(ah[rt], bh[ct], acc[rt][ct], 0, 0, 0);
        acc[rt][ct] = __builtin_amdgcn_mfma_f32_16x16x32_bf16(al[rt], bh[ct], acc[rt][ct], 0, 0, 0);
        acc[rt][ct] = __builtin_amdgcn_mfma_f32_16x16x32_bf16(ah[rt], bl[ct], acc[rt][ct], 0, 0, 0);
      }
  }
#pragma unroll
  for (int ct = 0; ct < 4; ++ct) {
    int gc = wc * 64 + ct * 16 + m;
    float s = 0.f, s2 = 0.f;
#pragma unroll
    for (int rt = 0; rt < 2; ++rt) {
      int grow = rbase + wr * 32 + rt * 16 + q * 4;
#pragma unroll
      for (int i = 0; i < 4; ++i) {
        float v = acc[rt][ct][i];
        s += v; s2 += v * v;
        if (grow + i < NN) t2[(long)(grow + i) * 128 + gc] = v; // d_out is exactly N x 128
      }
    }
    s  += __shfl_xor(s, 16);  s  += __shfl_xor(s, 32);
    s2 += __shfl_xor(s2, 16); s2 += __shfl_xor(s2, 32);
    if (q == 0) {
      unsafeAtomicAdd(&sum2s[slice * 128 + gc], s);
      unsafeAtomicAdd(&sq2s[slice * 128 + gc], s2);
    }
  }
}

// ---------------- apply (in-place on h buffer): h = BN2(t2), relu unless last
__global__ __launch_bounds__(256) void apply_kernel(float* hv,
                                                    const float* __restrict__ scale2,
                                                    const float* __restrict__ shift2,
                                                    int last) {
  int gid = blockIdx.x * 256 + threadIdx.x;
  int n = gid >> 5, qq = gid & 31;
  if (n >= NN) return;
  float4 u = *(const float4*)(hv + (long)n * 128 + qq * 4);
  float4 sc = *(const float4*)(scale2 + qq * 4);
  float4 sh = *(const float4*)(shift2 + qq * 4);
  float4 y;
  y.x = u.x * sc.x + sh.x;
  y.y = u.y * sc.y + sh.y;
  y.z = u.z * sc.z + sh.z;
  y.w = u.w * sc.w + sh.w;
  if (!last) {
    y.x = fmaxf(y.x, 0.f); y.y = fmaxf(y.y, 0.f);
    y.z = fmaxf(y.z, 0.f); y.w = fmaxf(y.w, 0.f);
  }
  *(float4*)(hv + (long)n * 128 + qq * 4) = y;
}

extern "C" void kernel_launch(void* const* d_in, const int* in_sizes, int n_in,
                              void* d_out, int out_size, void* d_ws, size_t ws_size,
                              hipStream_t stream) {
  (void)in_sizes; (void)n_in; (void)out_size; (void)ws_size;
  const int*   x      = (const int*)d_in[0];
  const int*   ei     = (const int*)d_in[1];
  const int*   ea     = (const int*)d_in[2];
  const float* ew     = (const float*)d_in[3];
  const float* aemb   = (const float*)d_in[4];
  const float* bemb   = (const float*)d_in[5];
  const float* eps    = (const float*)d_in[6];
  const float* W1     = (const float*)d_in[7];
  const float* g1     = (const float*)d_in[9];
  const float* bt1    = (const float*)d_in[10];
  const float* W2     = (const float*)d_in[11];
  const float* g_out  = (const float*)d_in[13];
  const float* bt_out = (const float*)d_in[14];

  float* h = (float*)d_out; // (N,128) f32; also holds t2 f32 between gemm2 and apply

  // ws layout (~109.0 MB; identical extent to round 5/6 — known in-bounds):
  //   [0, 51,249,152):            zh + zl (NP x 128 bf16 each)
  //   [51,249,152, 102,498,304):  t1h (NP x 256 bf16)
  //   [102,498,304 ...):          weights hi/lo, scale/shift, CSR; sliced stats alias dead `deg`
  char* ws = (char*)d_ws;
  unsigned short* zh  = (unsigned short*)(ws);
  unsigned short* zl  = (unsigned short*)(ws + 25624576);
  unsigned short* t1h = (unsigned short*)(ws + 51249152);
  unsigned short* w1h = (unsigned short*)(ws + 102498304);
  unsigned short* w1l = (unsigned short*)(ws + 102825984);
  unsigned short* w2h = (unsigned short*)(ws + 103153664);
  unsigned short* w2l = (unsigned short*)(ws + 103481344);
  float* ssbuf  = (float*)(ws + 103809024);               // 1536 f32: scale/shift
  int*   deg    = (int*)(ws + 103815168);                 // 100000 ints; dead after scan1
  int*   offs   = (int*)(ws + 104215168);                 // 100001 ints
  int*   cursor = (int*)(ws + 104615176);                 // 100000 ints
  int*   bsum   = (int*)(ws + 105015176);                 // 98 ints (pad 400)
  int*   pk     = (int*)(ws + 105015576);                 // 500000 ints
  float* wsrt   = (float*)(ws + 107015576);               // 500000 f32 -> ends 109,015,576

  float* scale1 = ssbuf;        float* shift1 = ssbuf + 256;
  float* scale2 = ssbuf + 512;  float* shift2 = ssbuf + 640;
  // sliced stat accumulators alias the dead deg region (needs 49,152 B of 400,000 B)
  float* slices = (float*)deg;                 // 12288 f32 total
  float* sum1s = slices;                       // 16*256
  float* sq1s  = slices + 4096;                // 16*256
  float* sum2s = slices + 8192;                // 16*128
  float* sq2s  = slices + 10240;               // 16*128

  prep_kernel<<<1280, 256, 0, stream>>>(W1, W2, w1h, w1l, w2h, w2l);
  zero_deg_kernel<<<391, 256, 0, stream>>>(deg);
  hist_kernel<<<1954, 256, 0, stream>>>(ei, deg);
  scan1_kernel<<<98, 256, 0, stream>>>(deg, offs, bsum);
  scan2_kernel<<<1, 64, 0, stream>>>(bsum, 98);
  scan3_kernel<<<392, 256, 0, stream>>>(offs, bsum, cursor);
  scatter_kernel<<<1954, 256, 0, stream>>>(ei, ea, ew, cursor, pk, wsrt);
  zero_slices_kernel<<<12, 256, 0, stream>>>(slices); // after scan1: deg is dead
  atom_kernel<<<12500, 256, 0, stream>>>(x, aemb, h);

  for (int l = 0; l < 5; ++l) {
    edge_agg_kernel<<<12512, 256, 0, stream>>>(offs, pk, wsrt, bemb + l * 3072, eps, l, h, zh, zl);
    gemm1_kernel<<<dim3(1564, 2), 256, 0, stream>>>(zh, zl, w1h + l * 32768, w1l + l * 32768, t1h, sum1s, sq1s);
    stats_kernel<<<1, 256, 0, stream>>>(sum1s, sq1s, g1 + l * 256, bt1 + l * 256, scale1, shift1, 256);
    gemm2_kernel<<<1564, 256, 0, stream>>>(t1h, scale1, shift1, w2h + l * 32768, w2l + l * 32768, h, sum2s, sq2s);
    stats_kernel<<<1, 128, 0, stream>>>(sum2s, sq2s, g_out + l * 128, bt_out + l * 128, scale2, shift2, 128);
    apply_kernel<<<12500, 256, 0, stream>>>(h, scale2, shift2, (l == 4) ? 1 : 0);
  }
}

// Round 8
// 961.704 us; speedup vs baseline: 1.7777x; 1.4410x over previous
//
#include <hip/hip_runtime.h>
#include <hip/hip_bf16.h>
#include <hip/hip_fp16.h>

#define NN 100000
#define EE 500000
#define NP 100096  // NN padded to 1564*64

typedef _Float16 f16;
typedef __attribute__((ext_vector_type(8))) _Float16 f16x8;
typedef __attribute__((ext_vector_type(4))) _Float16 f16x4;
typedef __attribute__((ext_vector_type(4))) float f32x4;

// ---------------- prep: W1 (L,128,256)->w1f [l][outcol][k] f16; W2 (L,256,128)->w2f [l][outcol][k] f16; bemb->f16
__global__ __launch_bounds__(256) void prep_kernel(const float* __restrict__ W1,
                                                   const float* __restrict__ W2,
                                                   const float* __restrict__ bemb,
                                                   f16* __restrict__ w1f,
                                                   f16* __restrict__ w2f,
                                                   f16* __restrict__ bembf) {
  int gid = blockIdx.x * 256 + threadIdx.x;
  if (gid < 163840) {
    int l = gid / 32768; int rem = gid % 32768;
    int k = rem / 256;   int n = rem % 256;
    w1f[l * 32768 + n * 128 + k] = (f16)W1[gid];
  } else if (gid < 327680) {
    int g = gid - 163840;
    int l = g / 32768; int rem = g % 32768;
    int j = rem / 128; int i = rem % 128;
    w2f[l * 32768 + i * 256 + j] = (f16)W2[g];
  } else if (gid < 343040) {
    int g = gid - 327680;
    bembf[g] = (f16)bemb[g];
  }
}

// ---------------- CSR build ----------------
__global__ __launch_bounds__(256) void zero_deg_kernel(int* __restrict__ deg) {
  int i = blockIdx.x * 256 + threadIdx.x;
  if (i < NN) deg[i] = 0;
}

__global__ __launch_bounds__(256) void hist_kernel(const int* __restrict__ ei, int* __restrict__ deg) {
  int e = blockIdx.x * 256 + threadIdx.x;
  if (e < EE) atomicAdd(&deg[ei[EE + e]], 1);
}

__global__ __launch_bounds__(256) void scan1_kernel(const int* __restrict__ deg,
                                                    int* __restrict__ offs,
                                                    int* __restrict__ bsum) {
  __shared__ int sh[256];
  int b = blockIdx.x, t = threadIdx.x;
  int base = b * 1024 + t * 4;
  int v[4];
  int s = 0;
#pragma unroll
  for (int i = 0; i < 4; ++i) { v[i] = (base + i < NN) ? deg[base + i] : 0; s += v[i]; }
  sh[t] = s;
  __syncthreads();
  for (int off = 1; off < 256; off <<= 1) {
    int x = (t >= off) ? sh[t - off] : 0;
    __syncthreads();
    sh[t] += x;
    __syncthreads();
  }
  int excl = sh[t] - s;
  if (t == 255) bsum[b] = sh[255];
  int run = excl;
#pragma unroll
  for (int i = 0; i < 4; ++i) {
    if (base + i < NN) offs[base + i] = run;
    run += v[i];
  }
}

__global__ void scan2_kernel(int* __restrict__ bsum, int nb) {
  if (threadIdx.x == 0 && blockIdx.x == 0) {
    int run = 0;
    for (int i = 0; i < nb; ++i) { int v = bsum[i]; bsum[i] = run; run += v; }
  }
}

__global__ __launch_bounds__(256) void scan3_kernel(int* __restrict__ offs,
                                                    const int* __restrict__ bsum,
                                                    int* __restrict__ cursor) {
  int i = blockIdx.x * 256 + threadIdx.x;
  if (i < NN) {
    int v = offs[i] + bsum[i >> 10];
    offs[i] = v;
    cursor[i] = v;
  } else if (i == NN) {
    offs[NN] = EE;
  }
}

// pk = src(17b) | a0<<17 | a1<<20 | a2<<23 ; wsrt = edge weight
__global__ __launch_bounds__(256) void scatter_kernel(const int* __restrict__ ei,
                                                      const int* __restrict__ ea,
                                                      const float* __restrict__ ew,
                                                      int* __restrict__ cursor,
                                                      int* __restrict__ pk,
                                                      float* __restrict__ wsrt) {
  int e = blockIdx.x * 256 + threadIdx.x;
  if (e >= EE) return;
  int dst = ei[EE + e];
  int pos = atomicAdd(&cursor[dst], 1);
  int src = ei[e];
  int a0 = ea[e * 3 + 0], a1 = ea[e * 3 + 1], a2 = ea[e * 3 + 2];
  pk[pos] = src | (a0 << 17) | (a1 << 20) | (a2 << 23);
  wsrt[pos] = ew[e];
}

// ---------------- zero the sliced stat accumulators (12288 f32) ----------------
__global__ __launch_bounds__(256) void zero_slices_kernel(float* __restrict__ p) {
  int i = blockIdx.x * 256 + threadIdx.x; // 12 blocks
  *(float4*)(p + i * 4) = float4{0.f, 0.f, 0.f, 0.f};
}

// ---------------- atom embedding: hf16[n,d] = (f16) sum_f atom_emb[f, x[n,f], d] ----------------
__global__ __launch_bounds__(256) void atom_kernel(const int* __restrict__ x,
                                                   const float* __restrict__ aemb,
                                                   f16* __restrict__ hf) {
  int gid = blockIdx.x * 256 + threadIdx.x;
  int n = gid >> 5, qq = gid & 31;
  if (n >= NN) return;
  float4 s = {0.f, 0.f, 0.f, 0.f};
#pragma unroll
  for (int f = 0; f < 9; ++f) {
    int xi = x[n * 9 + f];
    float4 v = *(const float4*)(aemb + (f * 120 + xi) * 128 + qq * 4);
    s.x += v.x; s.y += v.y; s.z += v.z; s.w += v.w;
  }
  f16x4 o;
  o[0] = (f16)s.x; o[1] = (f16)s.y; o[2] = (f16)s.z; o[3] = (f16)s.w;
  *(f16x4*)(hf + (long)n * 128 + qq * 4) = o;
}

// ---------------- edge aggregate (CSR, no atomics), fp16 gather:
// z[n] = (1+eps[l])*h[n] + sum relu(h[src]+bond_e)*w_e ; out f16; zero pad rows
__global__ __launch_bounds__(256) void edge_agg_kernel(const int* __restrict__ offs,
                                                       const int* __restrict__ pk,
                                                       const float* __restrict__ wsrt,
                                                       const f16* __restrict__ bembf, // + l*3072
                                                       const float* __restrict__ eps, int l,
                                                       const f16* __restrict__ hf,
                                                       f16* __restrict__ zb) {
  int gid = blockIdx.x * 256 + threadIdx.x; // NP*16 threads exactly
  int n = gid >> 4, d0 = (gid & 15) * 8;
  if (n >= NN) { // pad rows: zero so GEMM1 A-loads are branch-free
    f16x8 z = {0, 0, 0, 0, 0, 0, 0, 0};
    *(f16x8*)(zb + (long)n * 128 + d0) = z;
    return;
  }
  int s0 = offs[n], s1 = offs[n + 1];
  float e1 = 1.f + eps[l];
  f16x8 hn = *(const f16x8*)(hf + (long)n * 128 + d0);
  float acc[8];
#pragma unroll
  for (int i = 0; i < 8; ++i) acc[i] = e1 * (float)hn[i];
  for (int e = s0; e < s1; ++e) {
    int p = pk[e];
    float w = wsrt[e];
    int src = p & 131071;
    f16x8 b0 = *(const f16x8*)(bembf + (((p >> 17) & 7)) * 128 + d0);
    f16x8 b1 = *(const f16x8*)(bembf + (8 + ((p >> 20) & 7)) * 128 + d0);
    f16x8 b2 = *(const f16x8*)(bembf + (16 + ((p >> 23) & 7)) * 128 + d0);
    f16x8 hs = *(const f16x8*)(hf + (long)src * 128 + d0);
    f16x8 sm = hs + b0 + b1 + b2; // packed fp16 adds
#pragma unroll
    for (int i = 0; i < 8; ++i) {
      float sv = (float)sm[i];
      acc[i] += fmaxf(sv, 0.f) * w;
    }
  }
  f16x8 o;
#pragma unroll
  for (int i = 0; i < 8; ++i) o[i] = (f16)acc[i];
  *(f16x8*)(zb + (long)n * 128 + d0) = o;
}

// ---------------- GEMM1 (register-only fp16, 64x128 tiles, grid (1564,2)): t1 = z @ W1
// All 24 loads issued up-front (independent, branch-free), then 32 MFMAs.
__global__ __launch_bounds__(256) void gemm1_kernel(const f16* __restrict__ zb,
                                                    const f16* __restrict__ w1f,
                                                    f16* __restrict__ t1f,
                                                    float* __restrict__ sum1s,
                                                    float* __restrict__ sq1s) {
  const int tid = threadIdx.x;
  const int lane = tid & 63, w = tid >> 6;
  const int wr = w >> 1, wc = w & 1;
  const int m = lane & 15, q = lane >> 4;
  const int rbase = blockIdx.x * 64;
  const int cb = blockIdx.y;
  const int slice = blockIdx.x & 15;
  f32x4 acc[2][4];
  const f32x4 zf = {0.f, 0.f, 0.f, 0.f};
#pragma unroll
  for (int a = 0; a < 2; ++a)
#pragma unroll
    for (int b = 0; b < 4; ++b) acc[a][b] = zf;

  long aoff[2], boff[4];
#pragma unroll
  for (int rt = 0; rt < 2; ++rt)
    aoff[rt] = (long)(rbase + wr * 32 + rt * 16 + m) * 128 + q * 8;
#pragma unroll
  for (int ct = 0; ct < 4; ++ct)
    boff[ct] = (long)(cb * 128 + wc * 64 + ct * 16 + m) * 128 + q * 8;

  f16x8 A[2][4], B[4][4];
#pragma unroll
  for (int rt = 0; rt < 2; ++rt)
#pragma unroll
    for (int c = 0; c < 4; ++c)
      A[rt][c] = *(const f16x8*)(zb + aoff[rt] + c * 32);
#pragma unroll
  for (int ct = 0; ct < 4; ++ct)
#pragma unroll
    for (int c = 0; c < 4; ++c)
      B[ct][c] = *(const f16x8*)(w1f + boff[ct] + c * 32);

#pragma unroll
  for (int c = 0; c < 4; ++c)
#pragma unroll
    for (int rt = 0; rt < 2; ++rt)
#pragma unroll
      for (int ct = 0; ct < 4; ++ct)
        acc[rt][ct] = __builtin_amdgcn_mfma_f32_16x16x32_f16(A[rt][c], B[ct][c], acc[rt][ct], 0, 0, 0);

  // epilogue: f16 store (t1f has NP rows -> unmasked) + sliced column stats from f32 acc
#pragma unroll
  for (int ct = 0; ct < 4; ++ct) {
    int gc = cb * 128 + wc * 64 + ct * 16 + m;
    float s = 0.f, s2 = 0.f;
#pragma unroll
    for (int rt = 0; rt < 2; ++rt) {
      int grow = rbase + wr * 32 + rt * 16 + q * 4;
#pragma unroll
      for (int i = 0; i < 4; ++i) {
        float v = acc[rt][ct][i];
        s += v; s2 += v * v;
        t1f[(long)(grow + i) * 256 + gc] = (f16)v;
      }
    }
    s  += __shfl_xor(s, 16);  s  += __shfl_xor(s, 32);
    s2 += __shfl_xor(s2, 16); s2 += __shfl_xor(s2, 32);
    if (q == 0) {
      unsafeAtomicAdd(&sum1s[slice * 256 + gc], s);
      unsafeAtomicAdd(&sq1s[slice * 256 + gc], s2);
    }
  }
}

// ---------------- stats: reduce 16 slices, compute scale/shift, re-zero slices
__global__ void stats_kernel(float* __restrict__ sums, float* __restrict__ sqs,
                             const float* __restrict__ g, const float* __restrict__ bt,
                             float* __restrict__ scale, float* __restrict__ shift, int C) {
  int j = blockIdx.x * blockDim.x + threadIdx.x;
  if (j >= C) return;
  float s = 0.f, s2 = 0.f;
#pragma unroll
  for (int k = 0; k < 16; ++k) {
    s += sums[k * C + j]; s2 += sqs[k * C + j];
    sums[k * C + j] = 0.f; sqs[k * C + j] = 0.f; // ready for next layer
  }
  float mu = s * (1.f / NN);
  float var = s2 * (1.f / NN) - mu * mu;
  var = fmaxf(var, 0.f);
  float is = rsqrtf(var + 1e-5f);
  float sc = g[j] * is;
  scale[j] = sc;
  shift[j] = bt[j] - mu * sc;
}

// ---------------- bnapply (in-place): t1 <- relu(BN1(t1)) as f16; pad rows zeroed
__global__ __launch_bounds__(256) void bnapply_kernel(f16* __restrict__ t1f,
                                                      const float* __restrict__ scale1,
                                                      const float* __restrict__ shift1) {
  long idx = (long)(blockIdx.x * 256 + threadIdx.x) * 8; // NP*256 elems exactly
  int row = (int)(idx >> 8);
  f16x8 o;
  if (row >= NN) {
    f16x8 z = {0, 0, 0, 0, 0, 0, 0, 0};
    o = z; // zero pad rows: keeps gemm2 branch-free AND stats2 exact
  } else {
    int j0 = (int)(idx & 255);
    float4 sc0 = *(const float4*)(scale1 + j0);
    float4 sc1 = *(const float4*)(scale1 + j0 + 4);
    float4 sh0 = *(const float4*)(shift1 + j0);
    float4 sh1 = *(const float4*)(shift1 + j0 + 4);
    f16x8 u = *(const f16x8*)(t1f + idx);
    o[0] = (f16)fmaxf((float)u[0] * sc0.x + sh0.x, 0.f);
    o[1] = (f16)fmaxf((float)u[1] * sc0.y + sh0.y, 0.f);
    o[2] = (f16)fmaxf((float)u[2] * sc0.z + sh0.z, 0.f);
    o[3] = (f16)fmaxf((float)u[3] * sc0.w + sh0.w, 0.f);
    o[4] = (f16)fmaxf((float)u[4] * sc1.x + sh1.x, 0.f);
    o[5] = (f16)fmaxf((float)u[5] * sc1.y + sh1.y, 0.f);
    o[6] = (f16)fmaxf((float)u[6] * sc1.z + sh1.z, 0.f);
    o[7] = (f16)fmaxf((float)u[7] * sc1.w + sh1.w, 0.f);
  }
  *(f16x8*)(t1f + idx) = o;
}

// ---------------- GEMM2 (register-only fp16, 64x128 tiles, grid 1564): t2 = a1 @ W2
// a1 = bnapply'd t1 (pad rows zero). Out t2 f16 into zb (dead after gemm1). Two K-halves.
__global__ __launch_bounds__(256) void gemm2_kernel(const f16* __restrict__ a1,
                                                    const f16* __restrict__ w2f,
                                                    f16* __restrict__ zb,
                                                    float* __restrict__ sum2s,
                                                    float* __restrict__ sq2s) {
  const int tid = threadIdx.x;
  const int lane = tid & 63, w = tid >> 6;
  const int wr = w >> 1, wc = w & 1;
  const int m = lane & 15, q = lane >> 4;
  const int rbase = blockIdx.x * 64;
  const int slice = blockIdx.x & 15;
  f32x4 acc[2][4];
  const f32x4 zf = {0.f, 0.f, 0.f, 0.f};
#pragma unroll
  for (int a = 0; a < 2; ++a)
#pragma unroll
    for (int b = 0; b < 4; ++b) acc[a][b] = zf;

  long aoff[2], boff[4];
#pragma unroll
  for (int rt = 0; rt < 2; ++rt)
    aoff[rt] = (long)(rbase + wr * 32 + rt * 16 + m) * 256 + q * 8;
#pragma unroll
  for (int ct = 0; ct < 4; ++ct)
    boff[ct] = (long)(wc * 64 + ct * 16 + m) * 256 + q * 8;

#pragma unroll
  for (int hh = 0; hh < 2; ++hh) { // K=256 in two halves of 4 chunks
    f16x8 A[2][4], B[4][4];
#pragma unroll
    for (int rt = 0; rt < 2; ++rt)
#pragma unroll
      for (int c = 0; c < 4; ++c)
        A[rt][c] = *(const f16x8*)(a1 + aoff[rt] + (hh * 4 + c) * 32);
#pragma unroll
    for (int ct = 0; ct < 4; ++ct)
#pragma unroll
      for (int c = 0; c < 4; ++c)
        B[ct][c] = *(const f16x8*)(w2f + boff[ct] + (hh * 4 + c) * 32);
#pragma unroll
    for (int c = 0; c < 4; ++c)
#pragma unroll
      for (int rt = 0; rt < 2; ++rt)
#pragma unroll
        for (int ct = 0; ct < 4; ++ct)
          acc[rt][ct] = __builtin_amdgcn_mfma_f32_16x16x32_f16(A[rt][c], B[ct][c], acc[rt][ct], 0, 0, 0);
  }
#pragma unroll
  for (int ct = 0; ct < 4; ++ct) {
    int gc = wc * 64 + ct * 16 + m;
    float s = 0.f, s2 = 0.f;
#pragma unroll
    for (int rt = 0; rt < 2; ++rt) {
      int grow = rbase + wr * 32 + rt * 16 + q * 4;
#pragma unroll
      for (int i = 0; i < 4; ++i) {
        float v = acc[rt][ct][i];
        s += v; s2 += v * v; // pad rows contribute exactly 0 (a1 zeroed)
        zb[(long)(grow + i) * 128 + gc] = (f16)v; // zb has NP rows -> unmasked
      }
    }
    s  += __shfl_xor(s, 16);  s  += __shfl_xor(s, 32);
    s2 += __shfl_xor(s2, 16); s2 += __shfl_xor(s2, 32);
    if (q == 0) {
      unsafeAtomicAdd(&sum2s[slice * 128 + gc], s);
      unsafeAtomicAdd(&sq2s[slice * 128 + gc], s2);
    }
  }
}

// ---------------- apply: y = BN2(t2); l<4: hf16 = relu(y); l==4: d_out = y (f32)
__global__ __launch_bounds__(256) void apply_kernel(const f16* __restrict__ zb,
                                                    const float* __restrict__ scale2,
                                                    const float* __restrict__ shift2,
                                                    int last,
                                                    f16* __restrict__ hf,
                                                    float* __restrict__ outp) {
  int gid = blockIdx.x * 256 + threadIdx.x;
  int n = gid >> 5, qq = gid & 31;
  if (n >= NN) return;
  f16x4 u = *(const f16x4*)(zb + (long)n * 128 + qq * 4);
  float4 sc = *(const float4*)(scale2 + qq * 4);
  float4 sh = *(const float4*)(shift2 + qq * 4);
  float y0 = (float)u[0] * sc.x + sh.x;
  float y1 = (float)u[1] * sc.y + sh.y;
  float y2 = (float)u[2] * sc.z + sh.z;
  float y3 = (float)u[3] * sc.w + sh.w;
  if (last) {
    float4 o = {y0, y1, y2, y3};
    *(float4*)(outp + (long)n * 128 + qq * 4) = o;
  } else {
    f16x4 o;
    o[0] = (f16)fmaxf(y0, 0.f); o[1] = (f16)fmaxf(y1, 0.f);
    o[2] = (f16)fmaxf(y2, 0.f); o[3] = (f16)fmaxf(y3, 0.f);
    *(f16x4*)(hf + (long)n * 128 + qq * 4) = o;
  }
}

extern "C" void kernel_launch(void* const* d_in, const int* in_sizes, int n_in,
                              void* d_out, int out_size, void* d_ws, size_t ws_size,
                              hipStream_t stream) {
  (void)in_sizes; (void)n_in; (void)out_size; (void)ws_size;
  const int*   x      = (const int*)d_in[0];
  const int*   ei     = (const int*)d_in[1];
  const int*   ea     = (const int*)d_in[2];
  const float* ew     = (const float*)d_in[3];
  const float* aemb   = (const float*)d_in[4];
  const float* bemb   = (const float*)d_in[5];
  const float* eps    = (const float*)d_in[6];
  const float* W1     = (const float*)d_in[7];
  const float* g1     = (const float*)d_in[9];
  const float* bt1    = (const float*)d_in[10];
  const float* W2     = (const float*)d_in[11];
  const float* g_out  = (const float*)d_in[13];
  const float* bt_out = (const float*)d_in[14];

  float* outp = (float*)d_out; // final f32 output, written only at l==4

  // ws layout (ends ~108.44 MB < 109.0 MB known-good extent):
  //   [0, 25,624,576):             hf   (NP x 128 f16)
  //   [25,624,576, 51,249,152):    zb   (NP x 128 f16) — z / t2 alternately
  //   [51,249,152, 102,498,304):   t1f  (NP x 256 f16) — bnapply'd in place
  //   then weights f16, bemb f16, scale/shift, stat slices, CSR
  char* ws = (char*)d_ws;
  f16*   hf    = (f16*)(ws);
  f16*   zb    = (f16*)(ws + 25624576);
  f16*   t1f   = (f16*)(ws + 51249152);
  f16*   w1f   = (f16*)(ws + 102498304);  // 327,680 B
  f16*   w2f   = (f16*)(ws + 102825984);  // 327,680 B
  f16*   bembf = (f16*)(ws + 103153664);  // 30,720 B
  float* ssbuf = (float*)(ws + 103184384); // 768 f32 = 3,072 B
  float* slices= (float*)(ws + 103187456); // 12,288 f32 = 49,152 B
  int*   deg    = (int*)(ws + 103236608);  // 400,000 B
  int*   offs   = (int*)(ws + 103636608);  // 400,016 B (100,001 ints + pad)
  int*   cursor = (int*)(ws + 104036624);  // 400,000 B
  int*   bsum   = (int*)(ws + 104436624);  // 400 B
  int*   pk     = (int*)(ws + 104437024);  // 2,000,000 B
  float* wsrt   = (float*)(ws + 106437024);// 2,000,000 B -> ends 108,437,024

  float* scale1 = ssbuf;        float* shift1 = ssbuf + 256;
  float* scale2 = ssbuf + 512;  float* shift2 = ssbuf + 640;
  float* sum1s = slices;        // 16*256
  float* sq1s  = slices + 4096; // 16*256
  float* sum2s = slices + 8192; // 16*128
  float* sq2s  = slices + 10240;// 16*128

  prep_kernel<<<1340, 256, 0, stream>>>(W1, W2, bemb, w1f, w2f, bembf);
  zero_deg_kernel<<<391, 256, 0, stream>>>(deg);
  hist_kernel<<<1954, 256, 0, stream>>>(ei, deg);
  scan1_kernel<<<98, 256, 0, stream>>>(deg, offs, bsum);
  scan2_kernel<<<1, 64, 0, stream>>>(bsum, 98);
  scan3_kernel<<<392, 256, 0, stream>>>(offs, bsum, cursor);
  scatter_kernel<<<1954, 256, 0, stream>>>(ei, ea, ew, cursor, pk, wsrt);
  zero_slices_kernel<<<12, 256, 0, stream>>>(slices);
  atom_kernel<<<12500, 256, 0, stream>>>(x, aemb, hf);

  for (int l = 0; l < 5; ++l) {
    edge_agg_kernel<<<6256, 256, 0, stream>>>(offs, pk, wsrt, bembf + l * 3072, eps, l, hf, zb);
    gemm1_kernel<<<dim3(1564, 2), 256, 0, stream>>>(zb, w1f + l * 32768, t1f, sum1s, sq1s);
    stats_kernel<<<1, 256, 0, stream>>>(sum1s, sq1s, g1 + l * 256, bt1 + l * 256, scale1, shift1, 256);
    bnapply_kernel<<<12512, 256, 0, stream>>>(t1f, scale1, shift1);
    gemm2_kernel<<<1564, 256, 0, stream>>>(t1f, w2f + l * 32768, zb, sum2s, sq2s);
    stats_kernel<<<1, 128, 0, stream>>>(sum2s, sq2s, g_out + l * 128, bt_out + l * 128, scale2, shift2, 128);
    apply_kernel<<<12500, 256, 0, stream>>>(zb, scale2, shift2, (l == 4) ? 1 : 0, hf, outp);
  }
}